// Round 1
// 7079.953 us; speedup vs baseline: 1.3384x; 1.3384x over previous
//
#include <hip/hip_runtime.h>
#include <math.h>

#define T_ 32
#define B_ 16
#define NA 18
#define P_ 540   // 27*20

typedef __attribute__((ext_vector_type(8)))  short short8;
typedef __attribute__((ext_vector_type(16))) float f32x16;

__device__ __forceinline__ float sigm(float x){ return 1.0f/(1.0f+expf(-x)); }
__device__ __forceinline__ unsigned short f2bf(float f){
    unsigned u = __float_as_uint(f);
    u += 0x7fff + ((u>>16)&1u);
    return (unsigned short)(u>>16);
}
__device__ __forceinline__ float bfu(unsigned short u){ return __uint_as_float(((unsigned)u)<<16); }

// ---------------- conv1: (512,3,210,160) -> c1pad bf16 [512][32][56][42], k8 s4 padH(1,1) W(2,2)
__global__ __launch_bounds__(256) void conv1k(const float* __restrict__ frame,
                                              const float* __restrict__ w,
                                              const float* __restrict__ bias,
                                              unsigned short* __restrict__ c1pad){
    __shared__ float tile[4032];  // 3ch * 8rows * 168cols (padded)
    int bid = blockIdx.x;
    int n = bid / 52, oh = bid % 52;
    int tid = threadIdx.x;
    const float* fb = frame + (size_t)n*3*210*160;
    for (int s = tid; s < 4032; s += 256){
        int col = s % 168;
        int row = (s/168) & 7;
        int ic  = s / 1344;
        int iy = oh*4 - 1 + row;
        int ix = col - 2;
        float v = 0.f;
        if (iy >= 0 && iy < 210 && ix >= 0 && ix < 160) v = fb[ic*33600 + iy*160 + ix];
        tile[s] = v;
    }
    __syncthreads();
    int oc = tid & 31, grp = tid >> 5;      // grp 0..7 -> ow = grp*5..grp*5+4
    float acc[5] = {0.f,0.f,0.f,0.f,0.f};
    const float* wb = w + oc*192;
    for (int ic=0; ic<3; ++ic){
        #pragma unroll
        for (int kh=0; kh<8; ++kh){
            const float* wr = wb + ic*64 + kh*8;
            float4 w0 = *((const float4*)wr);
            float4 w1 = *((const float4*)(wr+4));
            const float* row = tile + ic*1344 + kh*168 + grp*20;
            float r[24];
            *((float4*)(r+ 0)) = *((const float4*)(row+ 0));
            *((float4*)(r+ 4)) = *((const float4*)(row+ 4));
            *((float4*)(r+ 8)) = *((const float4*)(row+ 8));
            *((float4*)(r+12)) = *((const float4*)(row+12));
            *((float4*)(r+16)) = *((const float4*)(row+16));
            *((float4*)(r+20)) = *((const float4*)(row+20));
            #pragma unroll
            for (int o=0;o<5;++o){
                acc[o] += r[o*4+0]*w0.x + r[o*4+1]*w0.y + r[o*4+2]*w0.z + r[o*4+3]*w0.w
                        + r[o*4+4]*w1.x + r[o*4+5]*w1.y + r[o*4+6]*w1.z + r[o*4+7]*w1.w;
            }
        }
    }
    float bi = bias[oc];
    unsigned short* ob = c1pad + ((size_t)(n*32 + oc)*56 + oh+2)*42 + 1;
    #pragma unroll
    for (int o=0;o<5;++o) ob[grp*5+o] = f2bf(acc[o] + bi);
}

// ---------------- conv2 A-pack: cnn_w2 (64,32,4,4) -> apack2[32 ic][2 mt][64 lane][8] bf16
__global__ void apack2k(const float* __restrict__ w2, unsigned short* __restrict__ ap){
    int idx = blockIdx.x*256 + threadIdx.x;
    if (idx >= 32768) return;
    int j = idx & 7;
    int lane = (idx>>3) & 63;
    int mt = (idx>>9) & 1;
    int ic = idx >> 10;
    int k = ((lane>>5)<<3) + j;          // kh*4+kw
    int oc = mt*32 + (lane & 31);
    ap[idx] = f2bf(w2[((oc*32 + ic)<<4) + k]);
}

// ---------------- conv2 MFMA: c1pad bf16 -> xpad bf16 [512][64][640], k4 s2 padH(2,2) W(1,1)
__global__ __launch_bounds__(256) void c2mfma(const unsigned short* __restrict__ c1pad,
                                              const unsigned short* __restrict__ apack2,
                                              const float* __restrict__ bias,
                                              unsigned short* __restrict__ xpad){
    __shared__ unsigned short p2[2][3072];   // [n 128][stride 24]
    __shared__ float bsm[64];
    int bid = blockIdx.x;
    int s = bid / 5;
    int n0 = (bid % 5) * 128;
    int tid = threadIdx.x;
    int wave = tid >> 6, lane = tid & 63;
    int khalf = (lane>>5) << 3;
    if (tid < 64) bsm[tid] = bias[tid];
    const unsigned short* cb = c1pad + (size_t)s*32*2352;

    int soff[8], swaddr[8];
    #pragma unroll
    for (int q=0;q<8;++q){
        int idx = q*256 + tid;
        int n = idx & 127, k = idx >> 7;
        int p = n0 + n; if (p > 539) p = 539;
        soff[q] = ((p/20)*2 + (k>>2))*42 + (p%20)*2 + (k&3);
        swaddr[q] = n*24 + k;
    }
    #pragma unroll
    for (int q=0;q<8;++q) p2[0][swaddr[q]] = cb[soff[q]];
    unsigned short rv[8];
    #pragma unroll
    for (int q=0;q<8;++q) rv[q] = cb[2352 + soff[q]];

    int mt = wave >> 1, ntb = (wave & 1) * 2;
    short8 acur = *((const short8*)(apack2 + ((size_t)mt*64 + lane)*8));
    short8 anxt;
    f32x16 acc[2];
    #pragma unroll
    for (int jj=0;jj<2;++jj)
        #pragma unroll
        for (int rg=0;rg<16;++rg) acc[jj][rg] = 0.f;
    __syncthreads();

    for (int c=0; c<32; ++c){
        int buf = c & 1;
        if (c < 31){
            #pragma unroll
            for (int q=0;q<8;++q) p2[buf^1][swaddr[q]] = rv[q];
        }
        if (c < 30){
            const unsigned short* src = cb + (size_t)(c+2)*2352;
            #pragma unroll
            for (int q=0;q<8;++q) rv[q] = src[soff[q]];
        }
        if (c < 31) anxt = *((const short8*)(apack2 + ((size_t)((c+1)*2 + mt)*64 + lane)*8));
        #pragma unroll
        for (int jj=0;jj<2;++jj){
            int n = (ntb+jj)*32 + (lane & 31);
            short8 bf = *((const short8*)(&p2[buf][n*24 + khalf]));
            acc[jj] = __builtin_amdgcn_mfma_f32_32x32x16_bf16(acur, bf, acc[jj], 0, 0, 0);
        }
        acur = anxt;
        __syncthreads();
    }
    #pragma unroll
    for (int jj=0;jj<2;++jj){
        int pos = n0 + (ntb+jj)*32 + (lane & 31);
        if (pos >= 540) continue;
        int y = pos/20, x = pos%20;
        unsigned short* op = xpad + (size_t)s*64*640 + (y+1)*22 + x + 1;
        #pragma unroll
        for (int rg=0; rg<16; ++rg){
            int oc = mt*32 + (rg & 3) + 8*(rg>>2) + 4*(lane>>5);
            op[(size_t)oc*640] = f2bf(acc[jj][rg] + bsm[oc]);
        }
    }
}

// ---------------- spatial basis S[540][64]
__global__ void sbasisk(float* __restrict__ S){
    int idx = blockIdx.x*256 + threadIdx.x;
    if (idx >= P_*64) return;
    int s = idx & 63, p = idx >> 6;
    int y = p/20, x = p%20;
    int u = s >> 3, v = s & 7;
    double a  = cos((double)((y+1)*(u+1)) * M_PI / 27.0);
    double bb = cos((double)((x+1)*(v+1)) * M_PI / 20.0);
    S[idx] = (float)(a*bb);
}

// ---------------- weight pack: f32 [R][C] -> bf16 [(R+3)/4][C][4]  (pad rows -> 0)
__global__ void packw4k(const float* __restrict__ in, unsigned short* __restrict__ out, int R, int C){
    int idx = blockIdx.x*256 + threadIdx.x;
    int r4cnt = (R+3)>>2;
    if (idx >= r4cnt*C*4) return;
    int j = idx & 3;
    int rc = idx >> 2;
    int c = rc % C;
    int r = (rc / C)*4 + j;
    out[idx] = (r < R) ? f2bf(in[(size_t)r*C + c]) : (unsigned short)0;
}
// ---------------- weight pack (transposed input): f32 [C][R] -> bf16 [(R+3)/4][C][4]
__global__ void packt4k(const float* __restrict__ in, unsigned short* __restrict__ out, int R, int C){
    int idx = blockIdx.x*256 + threadIdx.x;
    int r4cnt = (R+3)>>2;
    if (idx >= r4cnt*C*4) return;
    int j = idx & 3;
    int rc = idx >> 2;
    int c = rc % C;
    int r = (rc / C)*4 + j;
    out[idx] = (r < R) ? f2bf(in[(size_t)c*R + r]) : (unsigned short)0;
}

// ---------------- gates A-pack: lstm_w (512,192,3,3) -> apack[192][16][64][8] bf16 (k>=9 -> 0)
__global__ void apackk(const float* __restrict__ lw, unsigned short* __restrict__ ap){
    int idx = blockIdx.x*256 + threadIdx.x;
    if (idx >= 1572864) return;
    int j = idx & 7;
    int lane = (idx>>3) & 63;
    int mt = (idx>>9) & 15;
    int ch = idx >> 13;
    int kk = ((lane>>5)<<3) + j;
    int oc = mt*32 + (lane & 31);
    ap[idx] = (kk < 9) ? f2bf(lw[(size_t)oc*1728 + ch*9 + kk]) : (unsigned short)0;
}

// ---------------- pack conv_h0 fp32 -> hpad bf16 interior
__global__ void h0packk(const float* __restrict__ h0, unsigned short* __restrict__ hpad){
    int idx = blockIdx.x*256 + threadIdx.x;
    if (idx >= 16*128*540) return;
    int plane = idx / 540, p = idx % 540;
    hpad[(size_t)plane*640 + (p/20+1)*22 + (p%20) + 1] = f2bf(h0[idx]);
}

// ---------------- gates GEMM (bf16 MFMA 32x32x16), 4 chunks per barrier
__global__ __launch_bounds__(256) void gmfma(const unsigned short* __restrict__ xpad,
                                             const unsigned short* __restrict__ hpad,
                                             const unsigned short* __restrict__ apack,
                                             const unsigned char* __restrict__ done,
                                             float* __restrict__ gates,
                                             int t){
    __shared__ unsigned short panel[2][6144];   // 4 chunks x [n 64][stride 24]
    int bid = blockIdx.x;
    int b  = bid % 16;
    int r  = bid / 16;
    int nb = r % 9;
    int mh = r / 9;
    int tid = threadIdx.x;
    int wave = tid >> 6, lane = tid & 63;
    int khalf = (lane>>5) << 3;
    int n0 = nb * 64;
    bool dn = done[t*B_ + b];

    const unsigned short* xb = xpad + ((size_t)(t*B_ + b))*64*640;
    const unsigned short* hb = hpad + (size_t)b*128*640;

    int soff[9], swaddr[9], gq[9];
    #pragma unroll
    for (int q=0;q<9;++q){
        int idx = q*256 + tid;
        int g = idx / 576;
        int rr = idx % 576;
        int k = rr / 64, n = rr & 63;
        int p = n0 + n; if (p > 539) p = 539;
        int pbase = (p/20)*22 + (p%20);
        soff[q] = pbase + (k/3)*22 + (k%3);
        swaddr[q] = g*1536 + n*24 + k;
        gq[q] = g;
    }
    // zero padding k-rows 9..15 of both buffers
    for (int s2 = tid; s2 < 3584; s2 += 256){
        int bf2 = s2 / 1792, r2 = s2 % 1792;
        int g2 = r2 / 448, rr2 = r2 % 448;
        panel[bf2][g2*1536 + (rr2 & 63)*24 + 9 + (rr2>>6)] = 0;
    }
    #pragma unroll
    for (int q=0;q<9;++q) panel[0][swaddr[q]] = xb[gq[q]*640 + soff[q]];
    unsigned short rv[9];
    #pragma unroll
    for (int q=0;q<9;++q) rv[q] = xb[(4+gq[q])*640 + soff[q]];

    short8 acur[4][2], anxt[4][2];
    #pragma unroll
    for (int g=0;g<4;++g)
        #pragma unroll
        for (int i=0;i<2;++i){
            int mt = mh*8 + wave*2 + i;
            acur[g][i] = *((const short8*)(apack + ((size_t)(g*16 + mt)*64 + lane)*8));
        }

    f32x16 acc[2][2];
    #pragma unroll
    for (int j=0;j<2;++j)
        #pragma unroll
        for (int i=0;i<2;++i)
            #pragma unroll
            for (int rg=0;rg<16;++rg) acc[j][i][rg] = 0.f;

    __syncthreads();

    for (int it=0; it<48; ++it){
        int buf = it & 1;
        if (it < 47){
            #pragma unroll
            for (int q=0;q<9;++q) panel[buf^1][swaddr[q]] = rv[q];
        }
        if (it < 46){
            int icb = (it+2)*4;
            #pragma unroll
            for (int q=0;q<9;++q){
                int ic = icb + gq[q];
                rv[q] = (ic < 64) ? xb[ic*640 + soff[q]]
                                  : (dn ? (unsigned short)0 : hb[(ic-64)*640 + soff[q]]);
            }
        }
        if (it < 47){
            int cb2 = (it+1)*4;
            #pragma unroll
            for (int g=0;g<4;++g)
                #pragma unroll
                for (int i=0;i<2;++i){
                    int mt = mh*8 + wave*2 + i;
                    anxt[g][i] = *((const short8*)(apack + ((size_t)((cb2+g)*16 + mt)*64 + lane)*8));
                }
        }
        #pragma unroll
        for (int g=0;g<4;++g){
            #pragma unroll
            for (int j=0;j<2;++j){
                int n = j*32 + (lane & 31);
                short8 bf = *((const short8*)(&panel[buf][g*1536 + n*24 + khalf]));
                #pragma unroll
                for (int i=0;i<2;++i)
                    acc[j][i] = __builtin_amdgcn_mfma_f32_32x32x16_bf16(acur[g][i], bf, acc[j][i], 0, 0, 0);
            }
        }
        #pragma unroll
        for (int g=0;g<4;++g){ acur[g][0] = anxt[g][0]; acur[g][1] = anxt[g][1]; }
        __syncthreads();
    }

    float* gbase = gates + (size_t)b*512*544;
    #pragma unroll
    for (int j=0;j<2;++j){
        int col = n0 + j*32 + (lane & 31);
        if (col >= 544) continue;
        #pragma unroll
        for (int i=0;i<2;++i){
            int ocb = mh*256 + wave*64 + i*32 + 4*(lane>>5);
            #pragma unroll
            for (int rg=0; rg<16; ++rg){
                int row = (rg & 3) + 8*(rg>>2);
                gbase[(size_t)(ocb + row)*544 + col] = acc[j][i][rg];
            }
        }
    }
}

// ---------------- vis LSTM pointwise
__global__ __launch_bounds__(256) void vupdk(const float* __restrict__ gates,
                                             const float* __restrict__ lb,
                                             const unsigned char* __restrict__ done,
                                             float* __restrict__ vh, float* __restrict__ vc,
                                             unsigned short* __restrict__ hpad,
                                             unsigned short* __restrict__ hreA, int t){
    int idx = blockIdx.x*256 + threadIdx.x;   // 16*128*540
    int p = idx % 540;
    int c = (idx/540) & 127;
    int b = idx / (540*128);
    const float* gb = gates + (size_t)b*512*544;
    float gi = gb[(size_t)(      c)*544 + p] + lb[      c];
    float gf = gb[(size_t)(128 + c)*544 + p] + lb[128 + c];
    float go = gb[(size_t)(256 + c)*544 + p] + lb[256 + c];
    float gg = gb[(size_t)(384 + c)*544 + p] + lb[384 + c];
    float m  = done[t*B_ + b] ? 0.f : 1.f;
    float cold = vc[idx] * m;
    float cn = sigm(gf)*cold + sigm(gi)*tanhf(gg);
    float hn = sigm(go)*tanhf(cn);
    vc[idx] = cn;
    vh[idx] = hn;
    hpad[((size_t)b*128 + c)*640 + (p/20+1)*22 + (p%20) + 1] = f2bf(hn);
    int flat = c*540 + p;
    int pos = (flat/2560)*20 + (flat/128)%20;
    int ch  = flat & 127;
    hreA[((size_t)(t*B_ + b)*540 + pos)*128 + ch] = f2bf(hn);
}

// ---------------- core: full T loop in ONE dispatch. one block per b, 512 threads.
// Weights are bf16 x4-packed ([r/4][C][4]) so they stay L2-resident (2.68 MB total)
// and every load feeds 4 independent FMA chains.
__global__ __launch_bounds__(512) void corek2(const unsigned short* __restrict__ hreA,
                                              const float* __restrict__ S,
                                              const unsigned short* __restrict__ pq1, const float* __restrict__ qb1,
                                              const unsigned short* __restrict__ pq2, const float* __restrict__ qb2,
                                              const unsigned short* __restrict__ pq3, const float* __restrict__ qb3,
                                              const unsigned short* __restrict__ pa1, const float* __restrict__ ab1,
                                              const unsigned short* __restrict__ pa2, const float* __restrict__ ab2,
                                              const unsigned short* __restrict__ pih, const unsigned short* __restrict__ phh,
                                              const float* __restrict__ bih, const float* __restrict__ bhh,
                                              const float* __restrict__ reward, const int* __restrict__ lact,
                                              const unsigned char* __restrict__ done,
                                              const float* __restrict__ core_h0, const float* __restrict__ core_c0,
                                              float* __restrict__ ccb, float* __restrict__ outs){
    __shared__ __align__(16) float hs[256];
    __shared__ __align__(16) float cs[256];
    __shared__ __align__(16) float hs2[256];
    __shared__ __align__(16) float q1[128];
    __shared__ __align__(16) float q2[288];
    __shared__ __align__(16) float q3[288];
    __shared__ __align__(16) float elog[4][P_];
    __shared__ __align__(16) float red[32];
    __shared__ __align__(16) float ansv[1056];
    __shared__ __align__(16) float hid[512];
    __shared__ __align__(16) float cis[256];
    __shared__ __align__(16) float gb[1024];
    int b = blockIdx.x, tid = threadIdx.x;
    if (tid < 256){ hs[tid] = core_h0[b*256+tid]; cs[tid] = core_c0[b*256+tid]; }
    if (tid >= 256 && tid < 269) ansv[1043 + (tid-256)] = 0.f;   // pad rows of aw1 (x garbage) -> 0
    __syncthreads();

    for (int t = 0; t < T_; ++t){
        // ---- q1 = relu(hs @ qw1 + qb1)
        if (tid < 128){
            float a0=0.f,a1=0.f,a2=0.f,a3=0.f;
            for (int i4=0;i4<64;++i4){
                ushort4 w = *((const ushort4*)(pq1 + (size_t)((i4<<7)+tid)*4));
                float4 h4 = *((const float4*)(hs + i4*4));
                a0 += h4.x*bfu(w.x); a1 += h4.y*bfu(w.y);
                a2 += h4.z*bfu(w.z); a3 += h4.w*bfu(w.w);
            }
            q1[tid] = fmaxf(qb1[tid] + ((a0+a1)+(a2+a3)), 0.f);
        }
        __syncthreads();
        // ---- q2 = relu(q1 @ qw2 + qb2)
        if (tid < 288){
            float a0=0.f,a1=0.f,a2=0.f,a3=0.f;
            for (int i4=0;i4<32;++i4){
                ushort4 w = *((const ushort4*)(pq2 + (size_t)(i4*288+tid)*4));
                float4 h4 = *((const float4*)(q1 + i4*4));
                a0 += h4.x*bfu(w.x); a1 += h4.y*bfu(w.y);
                a2 += h4.z*bfu(w.z); a3 += h4.w*bfu(w.w);
            }
            q2[tid] = fmaxf(qb2[tid] + ((a0+a1)+(a2+a3)), 0.f);
        }
        __syncthreads();
        // ---- q3 = q2 @ qw3 + qb3
        if (tid < 288){
            float a0=0.f,a1=0.f,a2=0.f,a3=0.f;
            for (int i4=0;i4<72;++i4){
                ushort4 w = *((const ushort4*)(pq3 + (size_t)(i4*288+tid)*4));
                float4 h4 = *((const float4*)(q2 + i4*4));
                a0 += h4.x*bfu(w.x); a1 += h4.y*bfu(w.y);
                a2 += h4.z*bfu(w.z); a3 += h4.w*bfu(w.w);
            }
            float a = qb3[tid] + ((a0+a1)+(a2+a3));
            q3[tid] = a;
            ansv[736+tid] = a;
        }
        if (tid == 0){ float r = reward[t*B_+b]; ansv[1024] = fminf(1.f,fmaxf(-1.f,r)); }
        if (tid >= 32 && tid < 32+NA) ansv[1025 + tid-32] = (lact[t*B_+b] == tid-32) ? 1.f : 0.f;
        __syncthreads();

        // ---- attention logits
        const unsigned short* hrb = hreA + (size_t)(t*B_ + b)*540*128;
        for (int idx = tid; idx < 4*P_; idx += 512){
            int qi = idx / P_, p = idx % P_;
            const unsigned short* hp = hrb + (size_t)p*128;
            uint4 hv = *((const uint4*)hp);
            const float* qv = q3 + qi*72;
            float a = __uint_as_float(hv.x<<16)*qv[0] + __uint_as_float(hv.x & 0xffff0000u)*qv[1]
                    + __uint_as_float(hv.y<<16)*qv[2] + __uint_as_float(hv.y & 0xffff0000u)*qv[3]
                    + __uint_as_float(hv.z<<16)*qv[4] + __uint_as_float(hv.z & 0xffff0000u)*qv[5]
                    + __uint_as_float(hv.w<<16)*qv[6] + __uint_as_float(hv.w & 0xffff0000u)*qv[7];
            const float* Sp = S + p*64;
            #pragma unroll
            for (int s2=0;s2<16;++s2){
                float4 sv = *((const float4*)(Sp + 4*s2));
                a += sv.x*qv[8+4*s2] + sv.y*qv[9+4*s2] + sv.z*qv[10+4*s2] + sv.w*qv[11+4*s2];
            }
            elog[qi][p] = a;
        }
        __syncthreads();
        // ---- softmax (max, exp, sum) per query
        {
            int qi = tid >> 7, lt = tid & 127;
            float mx = -1e30f;
            for (int p = lt; p < P_; p += 128) mx = fmaxf(mx, elog[qi][p]);
            for (int off=32; off; off>>=1) mx = fmaxf(mx, __shfl_down(mx, off));
            if ((tid & 63) == 0) red[tid>>6] = mx;
            __syncthreads();
            if (tid < 4) red[16+tid] = fmaxf(red[2*tid], red[2*tid+1]);
            __syncthreads();
            mx = red[16+qi];
            float sm = 0.f;
            for (int p = lt; p < P_; p += 128){ float e = expf(elog[qi][p]-mx); elog[qi][p] = e; sm += e; }
            for (int off=32; off; off>>=1) sm += __shfl_down(sm, off);
            if ((tid & 63) == 0) red[8 + (tid>>6)] = sm;
            __syncthreads();
            if (tid < 4) red[24+tid] = red[8+2*tid] + red[8+2*tid+1];
            __syncthreads();
        }
        // ---- ans = softmax(A) @ V : vectorized (uint4/float4), 4-lane p-split + shfl reduce
        if (tid < 240){
            int g = tid >> 2;            // 60 groups: qi 0..3 x vb 0..14 (8 channels each)
            int qi = g / 15, vb = g % 15;
            int pc = tid & 3;
            float ac[8] = {0,0,0,0,0,0,0,0};
            const unsigned short* hb8 = hrb + 8 + vb*8;
            for (int p = pc*135; p < pc*135+135; ++p){
                float e = elog[qi][p];
                uint4 hv = *((const uint4*)(hb8 + (size_t)p*128));
                ac[0] += e*__uint_as_float(hv.x<<16);
                ac[1] += e*__uint_as_float(hv.x & 0xffff0000u);
                ac[2] += e*__uint_as_float(hv.y<<16);
                ac[3] += e*__uint_as_float(hv.y & 0xffff0000u);
                ac[4] += e*__uint_as_float(hv.z<<16);
                ac[5] += e*__uint_as_float(hv.z & 0xffff0000u);
                ac[6] += e*__uint_as_float(hv.w<<16);
                ac[7] += e*__uint_as_float(hv.w & 0xffff0000u);
            }
            #pragma unroll
            for (int j=0;j<8;++j){ ac[j] += __shfl_down(ac[j],2); ac[j] += __shfl_down(ac[j],1); }
            if ((tid&3)==0){
                float inv2 = 1.f/red[24+qi];
                #pragma unroll
                for (int j=0;j<8;++j) ansv[qi*184 + vb*8 + j] = ac[j]*inv2;
            }
        } else if (tid < 496){
            int u = tid - 240;
            int g = u >> 2;              // 64 groups: qi 0..3 x vb4 0..15 (4 floats of S each)
            int qi = g >> 4, vb4 = g & 15;
            int pc = u & 3;
            float ac[4] = {0,0,0,0};
            const float* Sp = S + vb4*4;
            for (int p = pc*135; p < pc*135+135; ++p){
                float e = elog[qi][p];
                float4 sv = *((const float4*)(Sp + (size_t)p*64));
                ac[0]+=e*sv.x; ac[1]+=e*sv.y; ac[2]+=e*sv.z; ac[3]+=e*sv.w;
            }
            #pragma unroll
            for (int j=0;j<4;++j){ ac[j] += __shfl_down(ac[j],2); ac[j] += __shfl_down(ac[j],1); }
            if ((tid&3)==0){
                float inv2 = 1.f/red[24+qi];
                #pragma unroll
                for (int j=0;j<4;++j) ansv[qi*184 + 120 + vb4*4 + j] = ac[j]*inv2;
            }
        }
        __syncthreads();
        // ---- hid = relu(ansv @ aw1 + ab1)
        {
            float a0=ab1[tid], a1=0.f, a2=0.f, a3=0.f;
            for (int i4=0;i4<261;++i4){
                ushort4 w = *((const ushort4*)(pa1 + (size_t)((i4<<9)+tid)*4));
                float4 av = *((const float4*)(ansv + i4*4));
                a0 += av.x*bfu(w.x); a1 += av.y*bfu(w.y);
                a2 += av.z*bfu(w.z); a3 += av.w*bfu(w.w);
            }
            hid[tid] = fmaxf((a0+a1)+(a2+a3), 0.f);
        }
        float m = done[t*B_+b] ? 0.f : 1.f;
        if (tid < 256) hs2[tid] = hs[tid]*m;
        __syncthreads();
        // ---- cis = hid @ aw2 + ab2
        if (tid < 256){
            float a0=ab2[tid],a1=0.f,a2=0.f,a3=0.f;
            for (int i4=0;i4<128;++i4){
                ushort4 w = *((const ushort4*)(pa2 + (size_t)((i4<<8)+tid)*4));
                float4 hv = *((const float4*)(hid + i4*4));
                a0 += hv.x*bfu(w.x); a1 += hv.y*bfu(w.y);
                a2 += hv.z*bfu(w.z); a3 += hv.w*bfu(w.w);
            }
            cis[tid] = (a0+a1)+(a2+a3);
        }
        __syncthreads();
        // ---- gates = cis @ w_ih^T + hs2 @ w_hh^T + b
        for (int g = tid; g < 1024; g += 512){
            float a0=bih[g]+bhh[g], a1=0.f, a2=0.f, a3=0.f;
            for (int i4=0;i4<64;++i4){
                ushort4 wi = *((const ushort4*)(pih + (size_t)((i4<<10)+g)*4));
                ushort4 wh = *((const ushort4*)(phh + (size_t)((i4<<10)+g)*4));
                float4 cv = *((const float4*)(cis + i4*4));
                float4 hv = *((const float4*)(hs2 + i4*4));
                a0 += cv.x*bfu(wi.x) + hv.x*bfu(wh.x);
                a1 += cv.y*bfu(wi.y) + hv.y*bfu(wh.y);
                a2 += cv.z*bfu(wi.z) + hv.z*bfu(wh.z);
                a3 += cv.w*bfu(wi.w) + hv.w*bfu(wh.w);
            }
            gb[g] = (a0+a1)+(a2+a3);
        }
        __syncthreads();
        if (tid < 256){
            float gi = gb[tid], gf = gb[256+tid], gg = gb[512+tid], go = gb[768+tid];
            float cold = cs[tid]*m;
            float cn = sigm(gf)*cold + sigm(gi)*tanhf(gg);
            float hn = sigm(go)*tanhf(cn);
            cs[tid] = cn;
            hs[tid] = hn;
            outs[(t*B_+b)*256+tid] = hn;
        }
        __syncthreads();
    }
    if (tid < 256) ccb[b*256+tid] = cs[tid];
}

// ---------------- heads
__global__ __launch_bounds__(64) void finalk(const float* __restrict__ outs,
                                             const float* __restrict__ pw, const float* __restrict__ pb,
                                             const float* __restrict__ vw, const float* __restrict__ vb,
                                             float* __restrict__ dout){
    int row = blockIdx.x, tid = threadIdx.x;
    __shared__ float os[256];
    __shared__ float lg[NA];
    for (int i=tid; i<256; i+=64) os[i] = outs[row*256+i];
    __syncthreads();
    if (tid < NA){
        float a = pb[tid];
        for (int i=0;i<256;++i) a += os[i]*pw[i*NA+tid];
        lg[tid] = a;
        dout[row*NA + tid] = a;
    } else if (tid == 32){
        float a = vb[0];
        for (int i=0;i<256;++i) a += os[i]*vw[i];
        dout[9216 + row] = a;
    }
    __syncthreads();
    if (tid == 0){
        int am = 0; float bv = lg[0];
        for (int j=1;j<NA;++j) if (lg[j] > bv){ bv = lg[j]; am = j; }
        dout[9728 + row] = (float)am;
    }
}

extern "C" void kernel_launch(void* const* d_in, const int* in_sizes, int n_in,
                              void* d_out, int out_size, void* d_ws, size_t ws_size,
                              hipStream_t stream) {
    const float* frame   = (const float*)d_in[0];
    const unsigned char* done = (const unsigned char*)d_in[1];
    const int*   lact    = (const int*)d_in[2];
    const float* reward  = (const float*)d_in[3];
    const float* core_h0 = (const float*)d_in[4];
    const float* core_c0 = (const float*)d_in[5];
    const float* conv_h0 = (const float*)d_in[6];
    const float* conv_c0 = (const float*)d_in[7];
    const float* cnn_w1  = (const float*)d_in[8];
    const float* cnn_b1  = (const float*)d_in[9];
    const float* cnn_w2  = (const float*)d_in[10];
    const float* cnn_b2  = (const float*)d_in[11];
    const float* lstm_w  = (const float*)d_in[12];
    const float* lstm_b  = (const float*)d_in[13];
    const float* qw1 = (const float*)d_in[14]; const float* qb1 = (const float*)d_in[15];
    const float* qw2 = (const float*)d_in[16]; const float* qb2 = (const float*)d_in[17];
    const float* qw3 = (const float*)d_in[18]; const float* qb3 = (const float*)d_in[19];
    const float* aw1 = (const float*)d_in[20]; const float* ab1 = (const float*)d_in[21];
    const float* aw2 = (const float*)d_in[22]; const float* ab2 = (const float*)d_in[23];
    const float* w_ih = (const float*)d_in[24]; const float* w_hh = (const float*)d_in[25];
    const float* b_ih = (const float*)d_in[26]; const float* b_hh = (const float*)d_in[27];
    const float* pw = (const float*)d_in[28]; const float* pb = (const float*)d_in[29];
    const float* vw = (const float*)d_in[30]; const float* vb = (const float*)d_in[31];

    float* ws = (float*)d_ws;
    float* dout = (float*)d_out;

    // ws layout (float offsets). c1pad [10,485,760 .. 29,753,344) is transient:
    // consumed by c2mfma, then hreA/apack/weight-packs are written into that range
    // (strictly after c2mfma in stream order).
    unsigned short* xpad   = (unsigned short*)ws;                         // 20,971,520 u16
    unsigned short* c1pad  = (unsigned short*)(ws + 10485760);            // 38,535,168 u16 (transient)
    unsigned short* hreA   = (unsigned short*)(ws + 10485760);            // 35,389,440 u16
    unsigned short* apack  = (unsigned short*)(ws + 28180480);            // 1,572,864 u16
    unsigned short* wpk    = (unsigned short*)(ws + 28966912);            // 1,342,464 u16 of packed weights
    unsigned short* pq1 = wpk;            // 32768
    unsigned short* pq2 = wpk + 32768;    // 36864
    unsigned short* pq3 = wpk + 69632;    // 82944
    unsigned short* pa1 = wpk + 152576;   // 534528
    unsigned short* pa2 = wpk + 687104;   // 131072
    unsigned short* pih = wpk + 818176;   // 262144
    unsigned short* phh = wpk + 1080320;  // ends 1,342,464 (< 1,572,864 capacity)
    unsigned short* hpad   = (unsigned short*)(ws + 29753344);            // 1,310,720 u16
    unsigned short* apack2 = (unsigned short*)(ws + 30408704);            // 32,768 u16
    float* gates = ws + 30425088;      // 4,456,448
    float* vh    = ws + 34881536;      // 1,105,920
    float* vc    = ws + 35987456;      // 1,105,920
    float* S     = ws + 37093376;      // 34,560
    float* outs  = ws + 37127936;      // 131,072
    float* ccb   = ws + 37259008;      // 4,096    (total 37,263,104 floats = 149 MB)

    // zero padded planes (interiors overwritten)
    hipMemsetAsync(xpad,  0, (size_t)20971520*2, stream);
    hipMemsetAsync(c1pad, 0, (size_t)38535168*2, stream);

    // CNN
    apack2k<<<128, 256, 0, stream>>>(cnn_w2, apack2);
    conv1k<<<512*52, 256, 0, stream>>>(frame, cnn_w1, cnn_b1, c1pad);
    c2mfma<<<2560, 256, 0, stream>>>(c1pad, apack2, cnn_b2, xpad);

    // c1pad is dead from here on — its range is reused below
    hipMemsetAsync(hpad, 0, (size_t)1310720*2, stream);
    sbasisk<<<135, 256, 0, stream>>>(S);
    apackk<<<6144, 256, 0, stream>>>(lstm_w, apack);
    // core-weight bf16 x4 packs (2.68 MB total -> L2-resident in corek2)
    packw4k<<<128,  256, 0, stream>>>(qw1, pq1, 256, 128);
    packw4k<<<144,  256, 0, stream>>>(qw2, pq2, 128, 288);
    packw4k<<<324,  256, 0, stream>>>(qw3, pq3, 288, 288);
    packw4k<<<2088, 256, 0, stream>>>(aw1, pa1, 1043, 512);
    packw4k<<<512,  256, 0, stream>>>(aw2, pa2, 512, 256);
    packt4k<<<1024, 256, 0, stream>>>(w_ih, pih, 256, 1024);
    packt4k<<<1024, 256, 0, stream>>>(w_hh, phh, 256, 1024);
    h0packk<<<4320, 256, 0, stream>>>(conv_h0, hpad);
    hipMemcpyAsync(vh,  conv_h0, (size_t)16*128*540*sizeof(float), hipMemcpyDeviceToDevice, stream);
    hipMemcpyAsync(vc,  conv_c0, (size_t)16*128*540*sizeof(float), hipMemcpyDeviceToDevice, stream);

    // phase A: vis ConvLSTM over all t
    for (int t = 0; t < T_; ++t){
        gmfma<<<288, 256, 0, stream>>>(xpad, hpad, apack, done, gates, t);
        vupdk<<<4320, 256, 0, stream>>>(gates, lstm_b, done, vh, vc, hpad, hreA, t);
    }

    // phase B: entire core recurrence in one dispatch
    corek2<<<16, 512, 0, stream>>>(hreA, S, pq1,qb1,pq2,qb2,pq3,qb3,
                                   pa1,ab1,pa2,ab2, pih,phh,b_ih,b_hh,
                                   reward, lact, done, core_h0, core_c0, ccb, outs);

    finalk<<<512, 64, 0, stream>>>(outs, pw, pb, vw, vb, dout);

    hipMemcpyAsync(dout + 10240,   outs + (size_t)31*B_*256, (size_t)16*256*sizeof(float), hipMemcpyDeviceToDevice, stream);
    hipMemcpyAsync(dout + 14336,   ccb, (size_t)16*256*sizeof(float), hipMemcpyDeviceToDevice, stream);
    hipMemcpyAsync(dout + 18432,   vh,  (size_t)16*128*540*sizeof(float), hipMemcpyDeviceToDevice, stream);
    hipMemcpyAsync(dout + 1124352, vc,  (size_t)16*128*540*sizeof(float), hipMemcpyDeviceToDevice, stream);
}